// Round 5
// baseline (281.881 us; speedup 1.0000x reference)
//
#include <hip/hip_runtime.h>
#include <hip/hip_cooperative_groups.h>

#define HW 4096
#define PADU 136     // ushort row stride for Y tiles (272 B, 16B-aligned)
typedef unsigned short ushort;
typedef __attribute__((ext_vector_type(8))) short short8;
typedef __attribute__((ext_vector_type(4))) float f32x4;

__device__ __forceinline__ ushort bf_rne(float f) {
  unsigned u = __float_as_uint(f);
  unsigned r = (u + 0x7fffu + ((u >> 16) & 1u)) >> 16;
  return (ushort)r;
}
__device__ __forceinline__ void split2(float f, ushort& hi, ushort& lo) {
  ushort h = bf_rne(f);
  float hf = __uint_as_float((unsigned)h << 16);
  hi = h;
  lo = bf_rne(f - hf);
}

// ---------------- prep: fold BN into pw weights, split everything to bf16 hi/lo ----
// roles: 0-7 W0 fold, 8-15 W1 fold, 16-23 wvp^T, 24-31 wop^T, 32-33 wom^T
__global__ __launch_bounds__(256) void prep(
    const float* __restrict__ g1, const float* __restrict__ be1,
    const float* __restrict__ m1, const float* __restrict__ v1,
    const float* __restrict__ w0,
    const float* __restrict__ g2, const float* __restrict__ be2,
    const float* __restrict__ m2, const float* __restrict__ v2,
    const float* __restrict__ w1,
    const float* __restrict__ wvp, const float* __restrict__ wom,
    const float* __restrict__ wop,
    ushort* __restrict__ W0h, ushort* __restrict__ W0l, float* __restrict__ b0,
    ushort* __restrict__ W1h, ushort* __restrict__ W1l, float* __restrict__ b1,
    ushort* __restrict__ vph, ushort* __restrict__ vpl,
    ushort* __restrict__ oph, ushort* __restrict__ opl,
    ushort* __restrict__ omh, ushort* __restrict__ oml)
{
  const int t = threadIdx.x;
  const int role = blockIdx.x;
  if (role < 16) {
    __shared__ float sc[128], sh[128], part[16][17];
    const int cv = role >> 3;
    const float* g  = cv ? g2 : g1;
    const float* be = cv ? be2 : be1;
    const float* mm = cv ? m2 : m1;
    const float* vv = cv ? v2 : v1;
    if (t < 128) {
      float s = g[t] / sqrtf(vv[t] + 1e-5f);
      sc[t] = s;
      sh[t] = be[t] - mm[t] * s;
    }
    __syncthreads();
    const float* ws = cv ? w1 : w0;
    ushort* dh = cv ? W1h : W0h;
    ushort* dl = cv ? W1l : W0l;
    float* bb  = cv ? b1 : b0;
    const int o = ((role & 7) << 4) + (t >> 4);
    const int kl = t & 15;
    float accb = 0.f;
    #pragma unroll
    for (int j = 0; j < 8; ++j) {
      const int k = (kl << 3) + j;
      const float wv = ws[o * 128 + k];
      ushort hi, lo;
      split2(wv * sc[k], hi, lo);
      dh[o * 128 + k] = hi;
      dl[o * 128 + k] = lo;
      accb = fmaf(wv, sh[k], accb);
    }
    part[t >> 4][kl] = accb;
    __syncthreads();
    if (kl == 0) {
      float s = 0.f;
      #pragma unroll
      for (int j = 0; j < 16; ++j) s += part[t >> 4][j];
      bb[o] = s;
    }
  } else if (role < 32) {
    const int rr = role & 7;
    const float* srcM = (role < 24) ? wvp : wop;
    ushort* dh = (role < 24) ? vph : oph;
    ushort* dl = (role < 24) ? vpl : opl;
    const int n = (rr << 4) + (t >> 4);
    const int kl = t & 15;
    #pragma unroll
    for (int j = 0; j < 8; ++j) {
      const int k = (kl << 3) + j;
      ushort hi, lo;
      split2(srcM[k * 128 + n], hi, lo);
      dh[n * 128 + k] = hi;
      dl[n * 128 + k] = lo;
    }
  } else {
    const int n = ((role - 32) << 4) + (t >> 4);   // 0..31
    const int kl = t & 15;
    #pragma unroll
    for (int j = 0; j < 8; ++j) {
      const int k = (kl << 3) + j;
      ushort hi, lo;
      split2(wom[k * 32 + n], hi, lo);
      omh[n * 128 + k] = hi;
      oml[n * 128 + k] = lo;
    }
  }
}

// ---------------- fused_all (cooperative): K1 phase -> grid.sync -> K2 phase -----
// grid(256) 1-D, 512 thr, 1 block/CU. b = blk&7 in BOTH phases: value[b]/omb[b]
// writes land in XCD-b L2 and the K2-phase sampler reads hit the same L2.
__global__ __launch_bounds__(512, 2) void fused_all(
    const float* __restrict__ x,
    const ushort* __restrict__ W0h, const ushort* __restrict__ W0l,
    const float* __restrict__ b0,
    const ushort* __restrict__ vph, const ushort* __restrict__ vpl,
    const float* __restrict__ bvp, const float* __restrict__ bom,
    float* __restrict__ value, float* __restrict__ omb,
    const ushort* __restrict__ oph, const ushort* __restrict__ opl,
    const ushort* __restrict__ W1h, const ushort* __restrict__ W1l,
    const float* __restrict__ b1, float* __restrict__ out)
{
  // K1 phase1: Wh[4][128][32]@0 (32768) Wl@32768 ; Xf[4][128][33] f32 @65536 -> 133120
  // K1 phase2: Yh[128][PADU]@0 (34816) Yl@34816; Vh[4][160][32]@69632 Vl@110592 -> 151552
  // K2 stage:  Afh[4][128][32]@0 Afl@32768; Bh@65536 Bl@98304; oms[128][32]@131072 -> 147456
  // K2 phase2: Yh@0 Yl@34816; W1h_[4][128][32]@69632 W1l_@102400 -> 135168
  __shared__ __align__(16) char smem[151552];
  __shared__ float b0_s[128], b2_s[160], b1_s[128];

  const int t = threadIdx.x;
  const int blk = blockIdx.x;
  const int b = blk & 7;            // batch<->XCD affinity (both phases)
  const int cb = blk >> 3;
  const int lane = t & 63, w = t >> 6;          // 8 waves
  const int col = lane & 15, quad = lane >> 4;
  const f32x4 z = {0.f, 0.f, 0.f, 0.f};

  // ================= K1 phase: x -(W0',b0)-> y2 -(wvp|wom)-> value,om ==========
  {
    ushort (*Wh_s)[128][32] = (ushort(*)[128][32])(smem);
    ushort (*Wl_s)[128][32] = (ushort(*)[128][32])(smem + 32768);
    float  (*Xf)[128][33]   = (float(*)[128][33])(smem + 65536);
    ushort (*Yh)[PADU]      = (ushort(*)[PADU])(smem);
    ushort (*Yl)[PADU]      = (ushort(*)[PADU])(smem + 34816);
    ushort (*Vh_s)[160][32] = (ushort(*)[160][32])(smem + 69632);
    ushort (*Vl_s)[160][32] = (ushort(*)[160][32])(smem + 110592);

    const int hwBase = cb << 7;
    const size_t xbase = (size_t)b * (size_t)(128 * HW);
    if (t < 128) b0_s[t] = b0[t];
    if (t < 160) b2_s[t] = (t < 128) ? bvp[t] : bom[t - 128];
    if (t < 128) b1_s[t] = b1[t];

    // T14: issue V-matrix loads now; LDS-write after phase-1 barrier
    uint4 vregH[5], vregL[5];
    #pragma unroll
    for (int ii = 0; ii < 5; ++ii) {
      const int i = (ii << 9) + t;
      const int kc = i / 640;
      const int r2 = i - kc * 640;
      const int n = r2 >> 2, q8 = (r2 & 3) << 3;
      vregH[ii] = *(const uint4*)&vph[n * 128 + (kc << 5) + q8];
      vregL[ii] = *(const uint4*)&vpl[n * 128 + (kc << 5) + q8];
    }

    // stage ALL phase-1 operands (W0 split + x transposed), one barrier
    {
      const int o = t >> 2, q8 = (t & 3) << 3;
      #pragma unroll
      for (int kc = 0; kc < 4; ++kc) {
        *(uint4*)&Wh_s[kc][o][q8] = *(const uint4*)&W0h[o * 128 + (kc << 5) + q8];
        *(uint4*)&Wl_s[kc][o][q8] = *(const uint4*)&W0l[o * 128 + (kc << 5) + q8];
      }
    }
    {
      float4 xr4[8];
      #pragma unroll
      for (int i = 0; i < 8; ++i) {
        const int idx8 = (i << 9) + t;                 // 0..4095
        xr4[i] = *(const float4*)&x[xbase + (size_t)(idx8 >> 5) * HW + hwBase + ((idx8 & 31) << 2)];
      }
      #pragma unroll
      for (int i = 0; i < 8; ++i) {
        const int idx8 = (i << 9) + t;
        const int ch = idx8 >> 5, j4 = (idx8 & 31) << 2;
        Xf[ch >> 5][j4 + 0][ch & 31] = xr4[i].x;
        Xf[ch >> 5][j4 + 1][ch & 31] = xr4[i].y;
        Xf[ch >> 5][j4 + 2][ch & 31] = xr4[i].z;
        Xf[ch >> 5][j4 + 3][ch & 31] = xr4[i].w;
      }
    }
    __syncthreads();

    // phase 1: C[o=128][j=128]; wave w owns j-strip [w*16, w*16+16)
    f32x4 acc1[8];
    #pragma unroll
    for (int f = 0; f < 8; ++f) acc1[f] = z;

    #pragma unroll 1
    for (int kc = 0; kc < 4; ++kc) {
      union { ushort u[8]; short8 v; } bh, bl;
      {
        const float* xr = Xf[kc][(w << 4) + col] + (quad << 3);
        #pragma unroll
        for (int j = 0; j < 8; ++j) split2(xr[j], bh.u[j], bl.u[j]);
      }
      #pragma unroll
      for (int f = 0; f < 8; ++f) {
        const int row = (f << 4) + col;
        const short8 aH = *(const short8*)&Wh_s[kc][row][quad << 3];
        const short8 aL = *(const short8*)&Wl_s[kc][row][quad << 3];
        acc1[f] = __builtin_amdgcn_mfma_f32_16x16x32_bf16(aH, bh.v, acc1[f], 0, 0, 0);
        acc1[f] = __builtin_amdgcn_mfma_f32_16x16x32_bf16(aH, bl.v, acc1[f], 0, 0, 0);
        acc1[f] = __builtin_amdgcn_mfma_f32_16x16x32_bf16(aL, bh.v, acc1[f], 0, 0, 0);
      }
    }
    __syncthreads();   // Xf/W dead; Y + V regions become live

    // V regs -> LDS; scatter y2 (+bias) pre-split into Yh/Yl[token o][feature j]
    #pragma unroll
    for (int ii = 0; ii < 5; ++ii) {
      const int i = (ii << 9) + t;
      const int kc = i / 640;
      const int r2 = i - kc * 640;
      const int n = r2 >> 2, q8 = (r2 & 3) << 3;
      *(uint4*)&Vh_s[kc][n][q8] = vregH[ii];
      *(uint4*)&Vl_s[kc][n][q8] = vregL[ii];
    }
    #pragma unroll
    for (int f = 0; f < 8; ++f)
      #pragma unroll
      for (int r = 0; r < 4; ++r) {
        const int o = (f << 4) + (quad << 2) + r;
        const int j = (w << 4) + col;
        ushort hi, lo;
        split2(acc1[f][r] + b0_s[o], hi, lo);
        Yh[o][j] = hi;
        Yl[o][j] = lo;
      }
    __syncthreads();

    // phase 2: [value|om][m=128 tokens][n=160]; waves: 4 m-strips x 2 n-halves
    const int wm2 = (w & 3) << 5;
    const int wn2 = (w >> 2) * 80;
    f32x4 acc2[2][5];
    #pragma unroll
    for (int i = 0; i < 2; ++i)
      #pragma unroll
      for (int j = 0; j < 5; ++j) acc2[i][j] = z;

    #pragma unroll 1
    for (int j2 = 0; j2 < 4; ++j2) {
      short8 aH[2], aL[2];
      #pragma unroll
      for (int f2 = 0; f2 < 2; ++f2) {
        const int row = wm2 + (f2 << 4) + col;
        aH[f2] = *(const short8*)&Yh[row][(j2 << 5) + (quad << 3)];
        aL[f2] = *(const short8*)&Yl[row][(j2 << 5) + (quad << 3)];
      }
      #pragma unroll
      for (int g2 = 0; g2 < 5; ++g2) {
        const int n = wn2 + (g2 << 4) + col;
        const short8 vh = *(const short8*)&Vh_s[j2][n][quad << 3];
        const short8 vl = *(const short8*)&Vl_s[j2][n][quad << 3];
        #pragma unroll
        for (int f2 = 0; f2 < 2; ++f2) {
          acc2[f2][g2] = __builtin_amdgcn_mfma_f32_16x16x32_bf16(aH[f2], vh, acc2[f2][g2], 0, 0, 0);
          acc2[f2][g2] = __builtin_amdgcn_mfma_f32_16x16x32_bf16(aH[f2], vl, acc2[f2][g2], 0, 0, 0);
          acc2[f2][g2] = __builtin_amdgcn_mfma_f32_16x16x32_bf16(aL[f2], vh, acc2[f2][g2], 0, 0, 0);
        }
      }
    }
    #pragma unroll
    for (int f2 = 0; f2 < 2; ++f2)
      #pragma unroll
      for (int r = 0; r < 4; ++r) {
        const int m = wm2 + (f2 << 4) + (quad << 2) + r;
        const size_t gRow = (size_t)b * HW + (size_t)m * 32 + cb;
        #pragma unroll
        for (int g2 = 0; g2 < 5; ++g2) {
          const int n = wn2 + (g2 << 4) + col;
          const float v = acc2[f2][g2][r] + b2_s[n];
          if (n < 128) value[gRow * 128 + n] = v;
          else         omb[gRow * 32 + (n - 128)] = v;
        }
      }
  }

  __threadfence();
  cooperative_groups::this_grid().sync();

  // ================= K2 phase: sample -(wop)-> xnew -(W1',b1)-> out ============
  {
    ushort (*Afh)[128][32]  = (ushort(*)[128][32])(smem);
    ushort (*Afl)[128][32]  = (ushort(*)[128][32])(smem + 32768);
    ushort (*Bh)[128][32]   = (ushort(*)[128][32])(smem + 65536);
    ushort (*Bl)[128][32]   = (ushort(*)[128][32])(smem + 98304);
    float  (*oms)[32]       = (float(*)[32])(smem + 131072);
    ushort (*Yh)[PADU]      = (ushort(*)[PADU])(smem);
    ushort (*Yl)[PADU]      = (ushort(*)[PADU])(smem + 34816);
    ushort (*W1h_)[128][32] = (ushort(*)[128][32])(smem + 69632);
    ushort (*W1l_)[128][32] = (ushort(*)[128][32])(smem + 102400);

    // stage: om rows for this block's 128 tokens + full B (wop^T split)
    {
      const int m0 = t >> 2, j8 = (t & 3) << 3;
      const size_t orow = ((size_t)b * HW + m0 * 32 + cb) * 32;
      *(float4*)&oms[m0][j8]     = *(const float4*)&omb[orow + j8];
      *(float4*)&oms[m0][j8 + 4] = *(const float4*)&omb[orow + j8 + 4];
    }
    #pragma unroll
    for (int i = 0; i < 4; ++i) {
      const int idx = (i << 9) + t;                    // 0..2047
      const int kc = idx >> 9, n = (idx >> 2) & 127, q8 = (idx & 3) << 3;
      *(uint4*)&Bh[kc][n][q8] = *(const uint4*)&oph[n * 128 + (kc << 5) + q8];
      *(uint4*)&Bl[kc][n][q8] = *(const uint4*)&opl[n * 128 + (kc << 5) + q8];
    }
    __syncthreads();

    // coalesced deformable bilinear sampling
    {
      const int xhalf = lane >> 5;                 // which x-corner this lane handles
      const int c4 = (lane & 31) << 2;             // 4-channel base
      const float* vb = value + (size_t)b * (size_t)(HW * 128) + c4;
      const int kcw = (lane & 31) >> 3;            // A-tile chunk for the write
      const int cow = (lane & 7) << 2;             // channel offset within chunk
      #pragma unroll 1
      for (int tt = 0; tt < 16; ++tt) {
        const int m = (w << 4) + tt;
        const int s = m * 32 + cb;
        const float fw = (float)(s & 63), fh = (float)(s >> 6);
        const float* omp = oms[m];
        float a0 = 0.f, a1 = 0.f, a2 = 0.f, a3 = 0.f;
        #pragma unroll
        for (int k = 0; k < 9; ++k) {
          const float dx = omp[k * 3 + 0];
          const float dy = omp[k * 3 + 1];
          const float mw = omp[k * 3 + 2];
          const float px = fw + (float)(k % 3 - 1) + dx;
          const float py = fh + (float)(k / 3 - 1) + dy;
          const float x0f = floorf(px), y0f = floorf(py);
          const float fx = px - x0f, fy = py - y0f;
          const int ix = (int)x0f + xhalf;
          const int iy = (int)y0f;
          const float wxm = (xhalf ? fx : 1.f - fx) * mw *
                            ((ix >= 0 && ix < 64) ? 1.f : 0.f);
          const int xc = min(max(ix, 0), 63);
          const int yc0 = min(max(iy, 0), 63);
          const int yc1 = min(max(iy + 1, 0), 63);
          const float w0 = wxm * (1.f - fy) * ((iy >= 0 && iy < 64) ? 1.f : 0.f);
          const float w1 = wxm * fy * ((iy + 1 >= 0 && iy + 1 < 64) ? 1.f : 0.f);
          const float4 v0 = *(const float4*)&vb[(size_t)((yc0 << 6) + xc) * 128];
          const float4 v1 = *(const float4*)&vb[(size_t)((yc1 << 6) + xc) * 128];
          a0 = fmaf(w0, v0.x, a0); a1 = fmaf(w0, v0.y, a1);
          a2 = fmaf(w0, v0.z, a2); a3 = fmaf(w0, v0.w, a3);
          a0 = fmaf(w1, v1.x, a0); a1 = fmaf(w1, v1.y, a1);
          a2 = fmaf(w1, v1.z, a2); a3 = fmaf(w1, v1.w, a3);
        }
        // combine the two x-corner halves (lane <-> lane^32)
        a0 += __shfl_xor(a0, 32); a1 += __shfl_xor(a1, 32);
        a2 += __shfl_xor(a2, 32); a3 += __shfl_xor(a3, 32);
        if (!xhalf) {
          ushort h0, l0, h1, l1, h2, l2, h3, l3;
          split2(a0, h0, l0); split2(a1, h1, l1);
          split2(a2, h2, l2); split2(a3, h3, l3);
          uint2 uh, ul;
          uh.x = (unsigned)h0 | ((unsigned)h1 << 16);
          uh.y = (unsigned)h2 | ((unsigned)h3 << 16);
          ul.x = (unsigned)l0 | ((unsigned)l1 << 16);
          ul.y = (unsigned)l2 | ((unsigned)l3 << 16);
          *(uint2*)&Afh[kcw][m][cow] = uh;
          *(uint2*)&Afl[kcw][m][cow] = ul;
        }
      }
    }
    __syncthreads();

    // phase 1: C[token=128][midch=128]; waves: 2 m-halves x 4 n-strips
    const int wm1 = (w & 1) << 6, wn1 = (w >> 1) << 5;
    f32x4 acc1[4][2];
    #pragma unroll
    for (int i = 0; i < 4; ++i) { acc1[i][0] = z; acc1[i][1] = z; }

    #pragma unroll 1
    for (int kc = 0; kc < 4; ++kc) {
      short8 aH[4], aL[4];
      #pragma unroll
      for (int f = 0; f < 4; ++f) {
        const int row = wm1 + (f << 4) + col;
        aH[f] = *(const short8*)&Afh[kc][row][quad << 3];
        aL[f] = *(const short8*)&Afl[kc][row][quad << 3];
      }
      #pragma unroll
      for (int g = 0; g < 2; ++g) {
        const int n = wn1 + (g << 4) + col;
        const short8 bh = *(const short8*)&Bh[kc][n][quad << 3];
        const short8 bl = *(const short8*)&Bl[kc][n][quad << 3];
        #pragma unroll
        for (int f = 0; f < 4; ++f) {
          acc1[f][g] = __builtin_amdgcn_mfma_f32_16x16x32_bf16(aH[f], bh, acc1[f][g], 0, 0, 0);
          acc1[f][g] = __builtin_amdgcn_mfma_f32_16x16x32_bf16(aH[f], bl, acc1[f][g], 0, 0, 0);
          acc1[f][g] = __builtin_amdgcn_mfma_f32_16x16x32_bf16(aL[f], bh, acc1[f][g], 0, 0, 0);
        }
      }
    }
    __syncthreads();   // A/B dead; Y + W1 regions become live

    // W1 -> LDS + scatter out2 pre-split into Yh/Yl[midch j][token ch]
    #pragma unroll
    for (int i = 0; i < 4; ++i) {
      const int n = t >> 2, q8 = (t & 3) << 3;
      *(uint4*)&W1h_[i][n][q8] = *(const uint4*)&W1h[n * 128 + (i << 5) + q8];
      *(uint4*)&W1l_[i][n][q8] = *(const uint4*)&W1l[n * 128 + (i << 5) + q8];
    }
    #pragma unroll
    for (int f = 0; f < 4; ++f)
      #pragma unroll
      for (int g = 0; g < 2; ++g)
        #pragma unroll
        for (int r = 0; r < 4; ++r) {
          const int ch = wm1 + (f << 4) + (quad << 2) + r;
          const int j  = wn1 + (g << 4) + col;
          ushort hi, lo;
          split2(acc1[f][g][r], hi, lo);
          Yh[j][ch] = hi;
          Yl[j][ch] = lo;
        }
    __syncthreads();

    // phase 2: out[o=128][j=128]; waves: 2 m-halves x 4 n-strips
    const int wm2 = (w & 1) << 6, wn2 = (w >> 1) << 5;
    f32x4 acc2[4][2];
    #pragma unroll
    for (int i = 0; i < 4; ++i) { acc2[i][0] = z; acc2[i][1] = z; }

    #pragma unroll 1
    for (int j2 = 0; j2 < 4; ++j2) {
      short8 aH[4], aL[4];
      #pragma unroll
      for (int f2 = 0; f2 < 4; ++f2) {
        const int row = wm2 + (f2 << 4) + col;
        aH[f2] = *(const short8*)&W1h_[j2][row][quad << 3];
        aL[f2] = *(const short8*)&W1l_[j2][row][quad << 3];
      }
      #pragma unroll
      for (int g2 = 0; g2 < 2; ++g2) {
        const int j = wn2 + (g2 << 4) + col;
        const short8 bh = *(const short8*)&Yh[j][(j2 << 5) + (quad << 3)];
        const short8 bl = *(const short8*)&Yl[j][(j2 << 5) + (quad << 3)];
        #pragma unroll
        for (int f2 = 0; f2 < 4; ++f2) {
          acc2[f2][g2] = __builtin_amdgcn_mfma_f32_16x16x32_bf16(aH[f2], bh, acc2[f2][g2], 0, 0, 0);
          acc2[f2][g2] = __builtin_amdgcn_mfma_f32_16x16x32_bf16(aH[f2], bl, acc2[f2][g2], 0, 0, 0);
          acc2[f2][g2] = __builtin_amdgcn_mfma_f32_16x16x32_bf16(aL[f2], bh, acc2[f2][g2], 0, 0, 0);
        }
      }
    }
    const size_t obase = (size_t)b * (size_t)(128 * HW) + ((size_t)cb << 7);
    #pragma unroll
    for (int f2 = 0; f2 < 4; ++f2)
      #pragma unroll
      for (int r = 0; r < 4; ++r) {
        const int o = wm2 + (f2 << 4) + (quad << 2) + r;
        #pragma unroll
        for (int g2 = 0; g2 < 2; ++g2) {
          const int j = wn2 + (g2 << 4) + col;
          out[obase + (size_t)o * HW + j] = acc2[f2][g2][r] + b1_s[o];
        }
      }
  }
}

extern "C" void kernel_launch(void* const* d_in, const int* in_sizes, int n_in,
                              void* d_out, int out_size, void* d_ws, size_t ws_size,
                              hipStream_t stream)
{
  const float* x    = (const float*)d_in[0];
  const float* g1   = (const float*)d_in[1];
  const float* be1  = (const float*)d_in[2];
  const float* m1   = (const float*)d_in[3];
  const float* v1   = (const float*)d_in[4];
  const float* wpw0 = (const float*)d_in[5];
  const float* wvp  = (const float*)d_in[6];
  const float* bvp  = (const float*)d_in[7];
  const float* womW = (const float*)d_in[8];
  const float* bom  = (const float*)d_in[9];
  const float* wop  = (const float*)d_in[10];
  const float* g2   = (const float*)d_in[11];
  const float* be2  = (const float*)d_in[12];
  const float* m2   = (const float*)d_in[13];
  const float* v2   = (const float*)d_in[14];
  const float* wpw1 = (const float*)d_in[15];

  char* ws = (char*)d_ws;
  float*  value = (float*) (ws + 0);          // 16 MB (b,s,cg) f32
  float*  omb   = (float*) (ws + 16777216);   //  4 MB (b,s,32) f32
  size_t o = 20971520;
  ushort* W0h = (ushort*)(ws + o); o += 32768;
  ushort* W0l = (ushort*)(ws + o); o += 32768;
  ushort* W1h = (ushort*)(ws + o); o += 32768;
  ushort* W1l = (ushort*)(ws + o); o += 32768;
  ushort* vph = (ushort*)(ws + o); o += 40960;  // 160 x 128 (value 128 rows + om 32 rows)
  ushort* vpl = (ushort*)(ws + o); o += 40960;
  ushort* oph = (ushort*)(ws + o); o += 32768;
  ushort* opl = (ushort*)(ws + o); o += 32768;
  float*  b0  = (float*)(ws + o);  o += 512;
  float*  b1  = (float*)(ws + o);
  ushort* omh = vph + 128 * 128;   // om rows live at n = 128..159 of the V matrix
  ushort* oml = vpl + 128 * 128;

  prep<<<34, 256, 0, stream>>>(g1, be1, m1, v1, wpw0, g2, be2, m2, v2, wpw1,
                               wvp, womW, wop,
                               W0h, W0l, b0, W1h, W1l, b1,
                               vph, vpl, oph, opl, omh, oml);

  float* outp = (float*)d_out;
  void* args[] = {
    (void*)&x, (void*)&W0h, (void*)&W0l, (void*)&b0,
    (void*)&vph, (void*)&vpl, (void*)&bvp, (void*)&bom,
    (void*)&value, (void*)&omb,
    (void*)&oph, (void*)&opl,
    (void*)&W1h, (void*)&W1l, (void*)&b1, (void*)&outp
  };
  hipLaunchCooperativeKernel(reinterpret_cast<void*>(fused_all),
                             dim3(256), dim3(512), args, 0, stream);
}

// Round 6
// 148.084 us; speedup vs baseline: 1.9035x; 1.9035x over previous
//
#include <hip/hip_runtime.h>

#define HW 4096
#define PADF 33      // f32 row stride for Xf
#define PADU 136     // ushort row stride for Y tiles (272 B, 16B-aligned)
typedef unsigned short ushort;
typedef __attribute__((ext_vector_type(8))) short short8;
typedef __attribute__((ext_vector_type(4))) float f32x4;

__device__ __forceinline__ ushort bf_rne(float f) {
  unsigned u = __float_as_uint(f);
  unsigned r = (u + 0x7fffu + ((u >> 16) & 1u)) >> 16;
  return (ushort)r;
}
__device__ __forceinline__ void split2(float f, ushort& hi, ushort& lo) {
  ushort h = bf_rne(f);
  float hf = __uint_as_float((unsigned)h << 16);
  hi = h;
  lo = bf_rne(f - hf);
}

// ---------------- prep: fold BN into pw weights, split everything to bf16 hi/lo ----
// roles: 0-7 W0 fold, 8-15 W1 fold, 16-23 wvp^T, 24-31 wop^T, 32-33 wom^T
__global__ __launch_bounds__(256) void prep(
    const float* __restrict__ g1, const float* __restrict__ be1,
    const float* __restrict__ m1, const float* __restrict__ v1,
    const float* __restrict__ w0,
    const float* __restrict__ g2, const float* __restrict__ be2,
    const float* __restrict__ m2, const float* __restrict__ v2,
    const float* __restrict__ w1,
    const float* __restrict__ wvp, const float* __restrict__ wom,
    const float* __restrict__ wop,
    ushort* __restrict__ W0h, ushort* __restrict__ W0l, float* __restrict__ b0,
    ushort* __restrict__ W1h, ushort* __restrict__ W1l, float* __restrict__ b1,
    ushort* __restrict__ vph, ushort* __restrict__ vpl,
    ushort* __restrict__ oph, ushort* __restrict__ opl,
    ushort* __restrict__ omh, ushort* __restrict__ oml)
{
  const int t = threadIdx.x;
  const int role = blockIdx.x;
  if (role < 16) {
    __shared__ float sc[128], sh[128], part[16][17];
    const int cv = role >> 3;
    const float* g  = cv ? g2 : g1;
    const float* be = cv ? be2 : be1;
    const float* mm = cv ? m2 : m1;
    const float* vv = cv ? v2 : v1;
    if (t < 128) {
      float s = g[t] / sqrtf(vv[t] + 1e-5f);
      sc[t] = s;
      sh[t] = be[t] - mm[t] * s;
    }
    __syncthreads();
    const float* ws = cv ? w1 : w0;
    ushort* dh = cv ? W1h : W0h;
    ushort* dl = cv ? W1l : W0l;
    float* bb  = cv ? b1 : b0;
    const int o = ((role & 7) << 4) + (t >> 4);
    const int kl = t & 15;
    float accb = 0.f;
    #pragma unroll
    for (int j = 0; j < 8; ++j) {
      const int k = (kl << 3) + j;
      const float wv = ws[o * 128 + k];
      ushort hi, lo;
      split2(wv * sc[k], hi, lo);
      dh[o * 128 + k] = hi;
      dl[o * 128 + k] = lo;
      accb = fmaf(wv, sh[k], accb);
    }
    part[t >> 4][kl] = accb;
    __syncthreads();
    if (kl == 0) {
      float s = 0.f;
      #pragma unroll
      for (int j = 0; j < 16; ++j) s += part[t >> 4][j];
      bb[o] = s;
    }
  } else if (role < 32) {
    const int rr = role & 7;
    const float* srcM = (role < 24) ? wvp : wop;
    ushort* dh = (role < 24) ? vph : oph;
    ushort* dl = (role < 24) ? vpl : opl;
    const int n = (rr << 4) + (t >> 4);
    const int kl = t & 15;
    #pragma unroll
    for (int j = 0; j < 8; ++j) {
      const int k = (kl << 3) + j;
      ushort hi, lo;
      split2(srcM[k * 128 + n], hi, lo);
      dh[n * 128 + k] = hi;
      dl[n * 128 + k] = lo;
    }
  } else {
    const int n = ((role - 32) << 4) + (t >> 4);   // 0..31
    const int kl = t & 15;
    #pragma unroll
    for (int j = 0; j < 8; ++j) {
      const int k = (kl << 3) + j;
      ushort hi, lo;
      split2(wom[k * 32 + n], hi, lo);
      omh[n * 128 + k] = hi;
      oml[n * 128 + k] = lo;
    }
  }
}

// ---------------- K1 (round-0 structure): x -(W0',b0)-> y2 -(wvp|wom)-> value,om
// grid (32, 8), 512 thr (8 waves). Token r = o*32+cb, feature k = hw - cb*128.
__global__ __launch_bounds__(512, 2) void fused_x_valom(
    const float* __restrict__ x,
    const ushort* __restrict__ W0h, const ushort* __restrict__ W0l,
    const float* __restrict__ b0,
    const ushort* __restrict__ vph, const ushort* __restrict__ vpl,
    const float* __restrict__ bvp, const float* __restrict__ bom,
    float* __restrict__ value, float* __restrict__ omb)
{
  // region A (0..33279): phase1 Wh@0(8192) Wl@8192 Xf@16384(16896 B)
  //                      phase2 Vh@0(10240) Vl@10240
  // region B: Yh@33280(34816) Yl@68096(34816)  -> total 102912
  __shared__ __align__(16) char smem[102912];
  __shared__ float b0_s[128], b2_s[160];
  ushort (*Wh_s)[32] = (ushort(*)[32])(smem);
  ushort (*Wl_s)[32] = (ushort(*)[32])(smem + 8192);
  float*  Xf         = (float*)(smem + 16384);
  ushort (*Vh_s)[32] = (ushort(*)[32])(smem);
  ushort (*Vl_s)[32] = (ushort(*)[32])(smem + 10240);
  ushort (*Yh)[PADU] = (ushort(*)[PADU])(smem + 33280);
  ushort (*Yl)[PADU] = (ushort(*)[PADU])(smem + 68096);

  const int t = threadIdx.x;
  const int cb = blockIdx.x;
  const int b = blockIdx.y;
  const int hwBase = cb << 7;
  const size_t xbase = (size_t)b * (size_t)(128 * HW);
  if (t < 128) b0_s[t] = b0[t];
  if (t < 160) b2_s[t] = (t < 128) ? bvp[t] : bom[t - 128];
  const int lane = t & 63, w = t >> 6;          // 8 waves
  const int col = lane & 15, quad = lane >> 4;
  const f32x4 z = {0.f, 0.f, 0.f, 0.f};

  // ---- phase 1: C[o=128][j=128]; wave w owns j-strip [w*16, w*16+16) ----
  f32x4 acc1[8];
  #pragma unroll
  for (int f = 0; f < 8; ++f) acc1[f] = z;

  for (int kc = 0; kc < 4; ++kc) {
    const int kB = kc << 5;
    {
      const int o = t >> 2, q8 = (t & 3) << 3;
      *(uint4*)&Wh_s[o][q8] = *(const uint4*)&W0h[o * 128 + kB + q8];
      *(uint4*)&Wl_s[o][q8] = *(const uint4*)&W0l[o * 128 + kB + q8];
    }
    #pragma unroll
    for (int p = 0; p < 2; ++p) {
      const int idx = (p << 9) + t;
      const int c = idx >> 5, j4 = (idx & 31) << 2;
      const float4 f = *(const float4*)&x[xbase + (size_t)(kB + c) * HW + hwBase + j4];
      Xf[(j4 + 0) * PADF + c] = f.x;
      Xf[(j4 + 1) * PADF + c] = f.y;
      Xf[(j4 + 2) * PADF + c] = f.z;
      Xf[(j4 + 3) * PADF + c] = f.w;
    }
    __syncthreads();
    union { ushort u[8]; short8 v; } bh, bl;
    {
      const float* xr = &Xf[((w << 4) + col) * PADF + (quad << 3)];
      #pragma unroll
      for (int j = 0; j < 8; ++j) split2(xr[j], bh.u[j], bl.u[j]);
    }
    #pragma unroll
    for (int f = 0; f < 8; ++f) {
      const int row = (f << 4) + col;
      const short8 aH = *(const short8*)&Wh_s[row][quad << 3];
      const short8 aL = *(const short8*)&Wl_s[row][quad << 3];
      acc1[f] = __builtin_amdgcn_mfma_f32_16x16x32_bf16(aH, bh.v, acc1[f], 0, 0, 0);
      acc1[f] = __builtin_amdgcn_mfma_f32_16x16x32_bf16(aH, bl.v, acc1[f], 0, 0, 0);
      acc1[f] = __builtin_amdgcn_mfma_f32_16x16x32_bf16(aL, bh.v, acc1[f], 0, 0, 0);
    }
    __syncthreads();
  }

  // scatter y2 (+bias) pre-split into Yh/Yl[token o][feature j]
  #pragma unroll
  for (int f = 0; f < 8; ++f)
    #pragma unroll
    for (int r = 0; r < 4; ++r) {
      const int o = (f << 4) + (quad << 2) + r;
      const int j = (w << 4) + col;
      ushort hi, lo;
      split2(acc1[f][r] + b0_s[o], hi, lo);
      Yh[o][j] = hi;
      Yl[o][j] = lo;
    }

  // ---- phase 2: [value|om][m=128 tokens][n=160]; waves: 4 m-strips x 2 n-halves ----
  const int wm2 = (w & 3) << 5;
  const int wn2 = (w >> 2) * 80;
  f32x4 acc2[2][5];
  #pragma unroll
  for (int i = 0; i < 2; ++i)
    #pragma unroll
    for (int j = 0; j < 5; ++j) acc2[i][j] = z;

  for (int j2 = 0; j2 < 4; ++j2) {
    for (int i = t; i < 640; i += 512) {
      const int n = i >> 2, q8 = (i & 3) << 3;
      *(uint4*)&Vh_s[n][q8] = *(const uint4*)&vph[n * 128 + (j2 << 5) + q8];
      *(uint4*)&Vl_s[n][q8] = *(const uint4*)&vpl[n * 128 + (j2 << 5) + q8];
    }
    __syncthreads();
    short8 aH[2], aL[2];
    #pragma unroll
    for (int f2 = 0; f2 < 2; ++f2) {
      const int row = wm2 + (f2 << 4) + col;
      aH[f2] = *(const short8*)&Yh[row][(j2 << 5) + (quad << 3)];
      aL[f2] = *(const short8*)&Yl[row][(j2 << 5) + (quad << 3)];
    }
    #pragma unroll
    for (int g2 = 0; g2 < 5; ++g2) {
      const int n = wn2 + (g2 << 4) + col;
      const short8 vh = *(const short8*)&Vh_s[n][quad << 3];
      const short8 vl = *(const short8*)&Vl_s[n][quad << 3];
      #pragma unroll
      for (int f2 = 0; f2 < 2; ++f2) {
        acc2[f2][g2] = __builtin_amdgcn_mfma_f32_16x16x32_bf16(aH[f2], vh, acc2[f2][g2], 0, 0, 0);
        acc2[f2][g2] = __builtin_amdgcn_mfma_f32_16x16x32_bf16(aH[f2], vl, acc2[f2][g2], 0, 0, 0);
        acc2[f2][g2] = __builtin_amdgcn_mfma_f32_16x16x32_bf16(aL[f2], vh, acc2[f2][g2], 0, 0, 0);
      }
    }
    __syncthreads();
  }
  #pragma unroll
  for (int f2 = 0; f2 < 2; ++f2)
    #pragma unroll
    for (int r = 0; r < 4; ++r) {
      const int m = wm2 + (f2 << 4) + (quad << 2) + r;
      const size_t gRow = (size_t)b * HW + (size_t)m * 32 + cb;
      #pragma unroll
      for (int g2 = 0; g2 < 5; ++g2) {
        const int n = wn2 + (g2 << 4) + col;
        const float v = acc2[f2][g2][r] + b2_s[n];
        if (n < 128) value[gRow * 128 + n] = v;
        else         omb[gRow * 32 + (n - 128)] = v;
      }
    }
}

// ---------------- K2: inline bilinear sample -(wop)-> xnew -(W1',b1)-> out --------
// grid (256) 1-D: b = blk&7 -> batch<->XCD affinity keeps value[b] (2 MB) in one L2.
// Coalesced sampler: wave w owns tokens w*16+tt; lanes = (xcorner=lane>>5) x
// (4 channels=(lane&31)*4); each load = one contiguous 512 B row slice.
__global__ __launch_bounds__(512, 2) void fused_sample_op_out(
    const float* __restrict__ value, const float* __restrict__ omb,
    const ushort* __restrict__ oph, const ushort* __restrict__ opl,
    const ushort* __restrict__ W1h, const ushort* __restrict__ W1l,
    const float* __restrict__ b1, float* __restrict__ out)
{
  // stage A: Afh[4][128][32]@0 (32768) Afl@32768 (->65536)
  //          Bh[4][128][32]@65536 (32768) Bl@98304 (->131072); oms[128][32] f32 @131072 (->147456)
  // phase2:  Yh@0 (34816) Yl@34816 (->69632); W1h_[4][128][32]@69632 W1l_@102400 (->135168)
  __shared__ __align__(16) char smem[147456];
  __shared__ float b1_s[128];
  ushort (*Afh)[128][32]  = (ushort(*)[128][32])(smem);
  ushort (*Afl)[128][32]  = (ushort(*)[128][32])(smem + 32768);
  ushort (*Bh)[128][32]   = (ushort(*)[128][32])(smem + 65536);
  ushort (*Bl)[128][32]   = (ushort(*)[128][32])(smem + 98304);
  float  (*oms)[32]       = (float(*)[32])(smem + 131072);
  ushort (*Yh)[PADU]      = (ushort(*)[PADU])(smem);
  ushort (*Yl)[PADU]      = (ushort(*)[PADU])(smem + 34816);
  ushort (*W1h_)[128][32] = (ushort(*)[128][32])(smem + 69632);
  ushort (*W1l_)[128][32] = (ushort(*)[128][32])(smem + 102400);

  const int t = threadIdx.x;
  const int blk = blockIdx.x;
  const int b = blk & 7;            // batch<->XCD affinity
  const int cb = blk >> 3;
  if (t < 128) b1_s[t] = b1[t];
  const int lane = t & 63, w = t >> 6;
  const int col = lane & 15, quad = lane >> 4;
  const f32x4 z = {0.f, 0.f, 0.f, 0.f};

  // ---- stage: om rows for this block's 128 tokens + full B (wop^T split) ----
  {
    const int m0 = t >> 2, j8 = (t & 3) << 3;
    const size_t orow = ((size_t)b * HW + m0 * 32 + cb) * 32;
    *(float4*)&oms[m0][j8]     = *(const float4*)&omb[orow + j8];
    *(float4*)&oms[m0][j8 + 4] = *(const float4*)&omb[orow + j8 + 4];
  }
  #pragma unroll
  for (int i = 0; i < 4; ++i) {
    const int idx = (i << 9) + t;                    // 0..2047
    const int kc = idx >> 9, n = (idx >> 2) & 127, q8 = (idx & 3) << 3;
    *(uint4*)&Bh[kc][n][q8] = *(const uint4*)&oph[n * 128 + (kc << 5) + q8];
    *(uint4*)&Bl[kc][n][q8] = *(const uint4*)&opl[n * 128 + (kc << 5) + q8];
  }
  __syncthreads();

  // ---- coalesced deformable bilinear sampling ----
  {
    const int xhalf = lane >> 5;                 // which x-corner this lane handles
    const int c4 = (lane & 31) << 2;             // 4-channel base
    const float* vb = value + (size_t)b * (size_t)(HW * 128) + c4;
    const int kcw = (lane & 31) >> 3;            // A-tile chunk for the write
    const int cow = (lane & 7) << 2;             // channel offset within chunk
    #pragma unroll 1
    for (int tt = 0; tt < 16; ++tt) {
      const int m = (w << 4) + tt;
      const int s = m * 32 + cb;
      const float fw = (float)(s & 63), fh = (float)(s >> 6);
      const float* omp = oms[m];
      float a0 = 0.f, a1 = 0.f, a2 = 0.f, a3 = 0.f;
      #pragma unroll
      for (int k = 0; k < 9; ++k) {
        const float dx = omp[k * 3 + 0];
        const float dy = omp[k * 3 + 1];
        const float mw = omp[k * 3 + 2];
        const float px = fw + (float)(k % 3 - 1) + dx;
        const float py = fh + (float)(k / 3 - 1) + dy;
        const float x0f = floorf(px), y0f = floorf(py);
        const float fx = px - x0f, fy = py - y0f;
        const int ix = (int)x0f + xhalf;
        const int iy = (int)y0f;
        const float wxm = (xhalf ? fx : 1.f - fx) * mw *
                          ((ix >= 0 && ix < 64) ? 1.f : 0.f);
        const int xc = min(max(ix, 0), 63);
        const int yc0 = min(max(iy, 0), 63);
        const int yc1 = min(max(iy + 1, 0), 63);
        const float w0 = wxm * (1.f - fy) * ((iy >= 0 && iy < 64) ? 1.f : 0.f);
        const float w1 = wxm * fy * ((iy + 1 >= 0 && iy + 1 < 64) ? 1.f : 0.f);
        const float4 v0 = *(const float4*)&vb[(size_t)((yc0 << 6) + xc) * 128];
        const float4 v1 = *(const float4*)&vb[(size_t)((yc1 << 6) + xc) * 128];
        a0 = fmaf(w0, v0.x, a0); a1 = fmaf(w0, v0.y, a1);
        a2 = fmaf(w0, v0.z, a2); a3 = fmaf(w0, v0.w, a3);
        a0 = fmaf(w1, v1.x, a0); a1 = fmaf(w1, v1.y, a1);
        a2 = fmaf(w1, v1.z, a2); a3 = fmaf(w1, v1.w, a3);
      }
      // combine the two x-corner halves (lane <-> lane^32)
      a0 += __shfl_xor(a0, 32); a1 += __shfl_xor(a1, 32);
      a2 += __shfl_xor(a2, 32); a3 += __shfl_xor(a3, 32);
      if (!xhalf) {
        ushort h0, l0, h1, l1, h2, l2, h3, l3;
        split2(a0, h0, l0); split2(a1, h1, l1);
        split2(a2, h2, l2); split2(a3, h3, l3);
        uint2 uh, ul;
        uh.x = (unsigned)h0 | ((unsigned)h1 << 16);
        uh.y = (unsigned)h2 | ((unsigned)h3 << 16);
        ul.x = (unsigned)l0 | ((unsigned)l1 << 16);
        ul.y = (unsigned)l2 | ((unsigned)l3 << 16);
        *(uint2*)&Afh[kcw][m][cow] = uh;
        *(uint2*)&Afl[kcw][m][cow] = ul;
      }
    }
  }
  __syncthreads();

  // ---- phase 1: C[token=128][midch=128]; waves: 2 m-halves x 4 n-strips ----
  const int wm1 = (w & 1) << 6, wn1 = (w >> 1) << 5;
  f32x4 acc1[4][2];
  #pragma unroll
  for (int i = 0; i < 4; ++i) { acc1[i][0] = z; acc1[i][1] = z; }

  #pragma unroll 1
  for (int kc = 0; kc < 4; ++kc) {
    short8 aH[4], aL[4];
    #pragma unroll
    for (int f = 0; f < 4; ++f) {
      const int row = wm1 + (f << 4) + col;
      aH[f] = *(const short8*)&Afh[kc][row][quad << 3];
      aL[f] = *(const short8*)&Afl[kc][row][quad << 3];
    }
    #pragma unroll
    for (int g = 0; g < 2; ++g) {
      const int n = wn1 + (g << 4) + col;
      const short8 bh = *(const short8*)&Bh[kc][n][quad << 3];
      const short8 bl = *(const short8*)&Bl[kc][n][quad << 3];
      #pragma unroll
      for (int f = 0; f < 4; ++f) {
        acc1[f][g] = __builtin_amdgcn_mfma_f32_16x16x32_bf16(aH[f], bh, acc1[f][g], 0, 0, 0);
        acc1[f][g] = __builtin_amdgcn_mfma_f32_16x16x32_bf16(aH[f], bl, acc1[f][g], 0, 0, 0);
        acc1[f][g] = __builtin_amdgcn_mfma_f32_16x16x32_bf16(aL[f], bh, acc1[f][g], 0, 0, 0);
      }
    }
  }
  __syncthreads();   // A/B dead; Y + W1 regions become live

  // W1 -> LDS + scatter out2 pre-split into Yh/Yl[midch j][token ch]
  #pragma unroll
  for (int i = 0; i < 4; ++i) {
    const int n = t >> 2, q8 = (t & 3) << 3;
    *(uint4*)&W1h_[i][n][q8] = *(const uint4*)&W1h[n * 128 + (i << 5) + q8];
    *(uint4*)&W1l_[i][n][q8] = *(const uint4*)&W1l[n * 128 + (i << 5) + q8];
  }
  #pragma unroll
  for (int f = 0; f < 4; ++f)
    #pragma unroll
    for (int g = 0; g < 2; ++g)
      #pragma unroll
      for (int r = 0; r < 4; ++r) {
        const int ch = wm1 + (f << 4) + (quad << 2) + r;
        const int j  = wn1 + (g << 4) + col;
        ushort hi, lo;
        split2(acc1[f][g][r], hi, lo);
        Yh[j][ch] = hi;
        Yl[j][ch] = lo;
      }
  __syncthreads();

  // ---- phase 2: out[o=128][j=128]; waves: 2 m-halves x 4 n-strips ----
  const int wm2 = (w & 1) << 6, wn2 = (w >> 1) << 5;
  f32x4 acc2[4][2];
  #pragma unroll
  for (int i = 0; i < 4; ++i) { acc2[i][0] = z; acc2[i][1] = z; }

  #pragma unroll 1
  for (int j2 = 0; j2 < 4; ++j2) {
    short8 aH[4], aL[4];
    #pragma unroll
    for (int f2 = 0; f2 < 4; ++f2) {
      const int row = wm2 + (f2 << 4) + col;
      aH[f2] = *(const short8*)&W1h_[j2][row][quad << 3];
      aL[f2] = *(const short8*)&W1l_[j2][row][quad << 3];
    }
    #pragma unroll
    for (int g2 = 0; g2 < 2; ++g2) {
      const int j = wn2 + (g2 << 4) + col;
      const short8 bh = *(const short8*)&Yh[j][(j2 << 5) + (quad << 3)];
      const short8 bl = *(const short8*)&Yl[j][(j2 << 5) + (quad << 3)];
      #pragma unroll
      for (int f2 = 0; f2 < 4; ++f2) {
        acc2[f2][g2] = __builtin_amdgcn_mfma_f32_16x16x32_bf16(aH[f2], bh, acc2[f2][g2], 0, 0, 0);
        acc2[f2][g2] = __builtin_amdgcn_mfma_f32_16x16x32_bf16(aH[f2], bl, acc2[f2][g2], 0, 0, 0);
        acc2[f2][g2] = __builtin_amdgcn_mfma_f32_16x16x32_bf16(aL[f2], bh, acc2[f2][g2], 0, 0, 0);
      }
    }
  }
  const size_t obase = (size_t)b * (size_t)(128 * HW) + ((size_t)cb << 7);
  #pragma unroll
  for (int f2 = 0; f2 < 4; ++f2)
    #pragma unroll
    for (int r = 0; r < 4; ++r) {
      const int o = wm2 + (f2 << 4) + (quad << 2) + r;
      #pragma unroll
      for (int g2 = 0; g2 < 2; ++g2) {
        const int j = wn2 + (g2 << 4) + col;
        out[obase + (size_t)o * HW + j] = acc2[f2][g2][r] + b1_s[o];
      }
    }
}

extern "C" void kernel_launch(void* const* d_in, const int* in_sizes, int n_in,
                              void* d_out, int out_size, void* d_ws, size_t ws_size,
                              hipStream_t stream)
{
  const float* x    = (const float*)d_in[0];
  const float* g1   = (const float*)d_in[1];
  const float* be1  = (const float*)d_in[2];
  const float* m1   = (const float*)d_in[3];
  const float* v1   = (const float*)d_in[4];
  const float* wpw0 = (const float*)d_in[5];
  const float* wvp  = (const float*)d_in[6];
  const float* bvp  = (const float*)d_in[7];
  const float* womW = (const float*)d_in[8];
  const float* bom  = (const float*)d_in[9];
  const float* wop  = (const float*)d_in[10];
  const float* g2   = (const float*)d_in[11];
  const float* be2  = (const float*)d_in[12];
  const float* m2   = (const float*)d_in[13];
  const float* v2   = (const float*)d_in[14];
  const float* wpw1 = (const float*)d_in[15];

  char* ws = (char*)d_ws;
  float*  value = (float*) (ws + 0);          // 16 MB (b,s,cg) f32
  float*  omb   = (float*) (ws + 16777216);   //  4 MB (b,s,32) f32
  size_t o = 20971520;
  ushort* W0h = (ushort*)(ws + o); o += 32768;
  ushort* W0l = (ushort*)(ws + o); o += 32768;
  ushort* W1h = (ushort*)(ws + o); o += 32768;
  ushort* W1l = (ushort*)(ws + o); o += 32768;
  ushort* vph = (ushort*)(ws + o); o += 40960;  // 160 x 128 (value 128 rows + om 32 rows)
  ushort* vpl = (ushort*)(ws + o); o += 40960;
  ushort* oph = (ushort*)(ws + o); o += 32768;
  ushort* opl = (ushort*)(ws + o); o += 32768;
  float*  b0  = (float*)(ws + o);  o += 512;
  float*  b1  = (float*)(ws + o);
  ushort* omh = vph + 128 * 128;   // om rows live at n = 128..159 of the V matrix
  ushort* oml = vpl + 128 * 128;

  prep<<<34, 256, 0, stream>>>(g1, be1, m1, v1, wpw0, g2, be2, m2, v2, wpw1,
                               wvp, womW, wop,
                               W0h, W0l, b0, W1h, W1l, b1,
                               vph, vpl, oph, opl, omh, oml);
  fused_x_valom<<<dim3(32, 8), 512, 0, stream>>>(x, W0h, W0l, b0, vph, vpl,
                                                 bvp, bom, value, omb);
  fused_sample_op_out<<<dim3(256), 512, 0, stream>>>(value, omb, oph, opl,
                                                     W1h, W1l, b1, (float*)d_out);
}